// Round 1
// baseline (1643.659 us; speedup 1.0000x reference)
//
#include <hip/hip_runtime.h>

// Problem geometry (fixed by the reference).
#define DD 160
#define HH 192
#define WW 160
constexpr int DHW   = DD * HH * WW;   // 4,915,200
constexpr int NSUB_ = DHW / 8;        // 614,400
constexpr int BB    = 2;
constexpr int NBLK2 = 2400;           // penalty grid: 2400*256 threads, 2 pts each

// ---------------------------------------------------------------------------
// Kernel 1: comp_disp = flow_inv + STN(flow_fwd, flow_inv)
// align_corners=True => sample location is voxel+flow directly; zeros padding.
// ---------------------------------------------------------------------------
__global__ __launch_bounds__(256) void compose_kernel(
    const float* __restrict__ flow_fwd,
    const float* __restrict__ flow_inv,
    float* __restrict__ comp) {
  int tid = blockIdx.x * 256 + threadIdx.x;
  if (tid >= BB * DHW) return;
  int b = tid / DHW;
  int v = tid - b * DHW;
  int x = v % WW;
  int y = (v / WW) % HH;
  int z = v / (WW * HH);

  const float* fi = flow_inv + (size_t)b * 3 * DHW;
  const float* ff = flow_fwd + (size_t)b * 3 * DHW;
  float fz = fi[v];
  float fy = fi[DHW + v];
  float fx = fi[2 * DHW + v];
  float lx = (float)x + fx, ly = (float)y + fy, lz = (float)z + fz;

  float x0f = floorf(lx), y0f = floorf(ly), z0f = floorf(lz);
  float wx = lx - x0f, wy = ly - y0f, wz = lz - z0f;
  int x0 = (int)x0f, y0 = (int)y0f, z0 = (int)z0f;

  float s0 = 0.f, s1 = 0.f, s2 = 0.f;
#pragma unroll
  for (int dz = 0; dz < 2; ++dz) {
    int zi = z0 + dz;
    if (zi < 0 || zi >= DD) continue;
    float wz_ = dz ? wz : 1.f - wz;
#pragma unroll
    for (int dy = 0; dy < 2; ++dy) {
      int yi = y0 + dy;
      if (yi < 0 || yi >= HH) continue;
      float wzy = wz_ * (dy ? wy : 1.f - wy);
#pragma unroll
      for (int dx = 0; dx < 2; ++dx) {
        int xi = x0 + dx;
        if (xi < 0 || xi >= WW) continue;
        float w = wzy * (dx ? wx : 1.f - wx);
        int lin = (zi * HH + yi) * WW + xi;
        s0 += w * ff[lin];
        s1 += w * ff[DHW + lin];
        s2 += w * ff[2 * DHW + lin];
      }
    }
  }
  float* cp = comp + (size_t)b * 3 * DHW;
  cp[v]           = fz + s0;
  cp[DHW + v]     = fy + s1;
  cp[2 * DHW + v] = fx + s2;
}

// ---------------------------------------------------------------------------
// Trilinear sample of 3-channel field, align_corners=False, border padding.
// ix = px * W/(W-1) - 0.5 (reference's normalize+unnormalize collapsed).
// ---------------------------------------------------------------------------
__device__ __forceinline__ void sample_border(const float* __restrict__ cp,
                                              float px, float py, float pz,
                                              float out[3]) {
  const float SX = (float)WW / (float)(WW - 1);
  const float SY = (float)HH / (float)(HH - 1);
  const float SZ = (float)DD / (float)(DD - 1);
  float ix = px * SX - 0.5f;
  float iy = py * SY - 0.5f;
  float iz = pz * SZ - 0.5f;
  float x0f = floorf(ix), y0f = floorf(iy), z0f = floorf(iz);
  float wx = ix - x0f, wy = iy - y0f, wz = iz - z0f;
  int x0 = (int)x0f, y0 = (int)y0f, z0 = (int)z0f;

  int xs[2], ys[2], zs[2];
  xs[0] = min(max(x0, 0), WW - 1);
  xs[1] = min(max(x0 + 1, 0), WW - 1);
  ys[0] = min(max(y0, 0), HH - 1);
  ys[1] = min(max(y0 + 1, 0), HH - 1);
  zs[0] = min(max(z0, 0), DD - 1);
  zs[1] = min(max(z0 + 1, 0), DD - 1);
  float wxs[2] = {1.f - wx, wx};
  float wys[2] = {1.f - wy, wy};
  float wzs[2] = {1.f - wz, wz};

  out[0] = 0.f; out[1] = 0.f; out[2] = 0.f;
#pragma unroll
  for (int dz = 0; dz < 2; ++dz) {
#pragma unroll
    for (int dy = 0; dy < 2; ++dy) {
      int base = (zs[dz] * HH + ys[dy]) * WW;
      float wzy = wzs[dz] * wys[dy];
#pragma unroll
      for (int dx = 0; dx < 2; ++dx) {
        float w = wzy * wxs[dx];
        int lin = base + xs[dx];
        out[0] += w * cp[lin];
        out[1] += w * cp[DHW + lin];
        out[2] += w * cp[2 * DHW + lin];
      }
    }
  }
}

// ---------------------------------------------------------------------------
// Kernel 2: per-point penalty  sum_a |s(p+dx_a e_a) - s(p)|^2 / dx_a^2,
// block-reduced into partial[] (deterministic: fixed grid).
// ---------------------------------------------------------------------------
__global__ __launch_bounds__(256) void penalty_kernel(
    const float* __restrict__ comp,
    const int* __restrict__ idx,
    float* __restrict__ partial) {
  const float dxa = (float)(DD - 1) * 1e-3f;  // shift on x (axis 0)
  const float dyb = (float)(HH - 1) * 1e-3f;  // shift on y (axis 1)
  const float dzc = (float)(WW - 1) * 1e-3f;  // shift on z (axis 2)
  const float inv_dxa2 = 1.f / (dxa * dxa);
  const float inv_dyb2 = 1.f / (dyb * dyb);
  const float inv_dzc2 = 1.f / (dzc * dzc);

  int t = blockIdx.x * 256 + threadIdx.x;
  const int total = BB * NSUB_;
  float acc = 0.f;
  for (int i = t; i < total; i += NBLK2 * 256) {
    int b = i / NSUB_;
    int n = i - b * NSUB_;
    int id = idx[n];
    float x = (float)(id % WW);
    float y = (float)((id / WW) % HH);
    float z = (float)(id / (WW * HH));
    const float* cp = comp + (size_t)b * 3 * DHW;

    float s0[3], sa[3];
    sample_border(cp, x, y, z, s0);

    sample_border(cp, x + dxa, y, z, sa);
    {
      float d0 = sa[0] - s0[0], d1 = sa[1] - s0[1], d2 = sa[2] - s0[2];
      acc += (d0 * d0 + d1 * d1 + d2 * d2) * inv_dxa2;
    }
    sample_border(cp, x, y + dyb, z, sa);
    {
      float d0 = sa[0] - s0[0], d1 = sa[1] - s0[1], d2 = sa[2] - s0[2];
      acc += (d0 * d0 + d1 * d1 + d2 * d2) * inv_dyb2;
    }
    sample_border(cp, x, y, z + dzc, sa);
    {
      float d0 = sa[0] - s0[0], d1 = sa[1] - s0[1], d2 = sa[2] - s0[2];
      acc += (d0 * d0 + d1 * d1 + d2 * d2) * inv_dzc2;
    }
  }

  // block reduce (wave64 shuffle + LDS across 4 waves)
#pragma unroll
  for (int off = 32; off > 0; off >>= 1) acc += __shfl_down(acc, off);
  __shared__ float smem[4];
  int lane = threadIdx.x & 63, wid = threadIdx.x >> 6;
  if (lane == 0) smem[wid] = acc;
  __syncthreads();
  if (threadIdx.x == 0)
    partial[blockIdx.x] = smem[0] + smem[1] + smem[2] + smem[3];
}

__global__ __launch_bounds__(256) void finalize_kernel(
    const float* __restrict__ partial, float* __restrict__ out) {
  float v = 0.f;
  for (int i = threadIdx.x; i < NBLK2; i += 256) v += partial[i];
#pragma unroll
  for (int off = 32; off > 0; off >>= 1) v += __shfl_down(v, off);
  __shared__ float smem[4];
  int lane = threadIdx.x & 63, wid = threadIdx.x >> 6;
  if (lane == 0) smem[wid] = v;
  __syncthreads();
  if (threadIdx.x == 0) {
    float tot = smem[0] + smem[1] + smem[2] + smem[3];
    out[0] = tot / (float)(BB * NSUB_);
  }
}

// ---------------------------------------------------------------------------
extern "C" void kernel_launch(void* const* d_in, const int* in_sizes, int n_in,
                              void* d_out, int out_size, void* d_ws, size_t ws_size,
                              hipStream_t stream) {
  const float* flow_fwd = (const float*)d_in[0];
  const float* flow_inv = (const float*)d_in[1];
  const int*   idx      = (const int*)d_in[2];
  float* out = (float*)d_out;

  // ws layout: comp_disp [2*3*DHW floats = 118 MB] then partial [NBLK2 floats]
  float* comp    = (float*)d_ws;
  float* partial = comp + (size_t)BB * 3 * DHW;

  compose_kernel<<<(BB * DHW + 255) / 256, 256, 0, stream>>>(flow_fwd, flow_inv, comp);
  penalty_kernel<<<NBLK2, 256, 0, stream>>>(comp, idx, partial);
  finalize_kernel<<<1, 256, 0, stream>>>(partial, out);
}

// Round 2
// 506.770 us; speedup vs baseline: 3.2434x; 3.2434x over previous
//
#include <hip/hip_runtime.h>

// Problem geometry (fixed by the reference).
#define DD 160
#define HH 192
#define WW 160
constexpr int DHW   = DD * HH * WW;   // 4,915,200
constexpr int NSUB_ = DHW / 8;        // 614,400
constexpr int BB    = 2;
constexpr int NPBLK = 4800;           // penalty: 1 pt/thread, 4800*256 = 2*NSUB_

// ---------------------------------------------------------------------------
// Kernel 1: comp = flow_inv + STN(flow_fwd, flow_inv), written INTERLEAVED
// with per-voxel stride ST floats (ST=4 -> float4 stores, ST=3 -> 12B).
// align_corners=True => sample location is voxel+flow directly; zeros padding
// done branchlessly via clamped index + masked weight.
// ---------------------------------------------------------------------------
template <int ST>
__global__ __launch_bounds__(256) void compose_kernel(
    const float* __restrict__ flow_fwd,
    const float* __restrict__ flow_inv,
    float* __restrict__ comp) {
  int tid = blockIdx.x * 256 + threadIdx.x;
  if (tid >= BB * DHW) return;
  int b = tid / DHW;
  int v = tid - b * DHW;
  int x = v % WW;
  int y = (v / WW) % HH;
  int z = v / (WW * HH);

  const float* fi = flow_inv + (size_t)b * 3 * DHW;
  const float* ff = flow_fwd + (size_t)b * 3 * DHW;
  float fz = fi[v];
  float fy = fi[DHW + v];
  float fx = fi[2 * DHW + v];
  float lx = (float)x + fx, ly = (float)y + fy, lz = (float)z + fz;

  float x0f = floorf(lx), y0f = floorf(ly), z0f = floorf(lz);
  float wx = lx - x0f, wy = ly - y0f, wz = lz - z0f;
  int x0 = (int)x0f, y0 = (int)y0f, z0 = (int)z0f;

  // clamped indices + validity masks (zeros padding)
  int xq[2], yq[2], zq[2];
  float wxs[2], wys[2], wzs[2];
  xq[0] = min(max(x0, 0), WW - 1);     xq[1] = min(max(x0 + 1, 0), WW - 1);
  yq[0] = min(max(y0, 0), HH - 1);     yq[1] = min(max(y0 + 1, 0), HH - 1);
  zq[0] = min(max(z0, 0), DD - 1);     zq[1] = min(max(z0 + 1, 0), DD - 1);
  wxs[0] = (x0 >= 0 && x0 < WW) ? 1.f - wx : 0.f;
  wxs[1] = (x0 + 1 >= 0 && x0 + 1 < WW) ? wx : 0.f;
  wys[0] = (y0 >= 0 && y0 < HH) ? 1.f - wy : 0.f;
  wys[1] = (y0 + 1 >= 0 && y0 + 1 < HH) ? wy : 0.f;
  wzs[0] = (z0 >= 0 && z0 < DD) ? 1.f - wz : 0.f;
  wzs[1] = (z0 + 1 >= 0 && z0 + 1 < DD) ? wz : 0.f;

  float s0 = 0.f, s1 = 0.f, s2 = 0.f;
#pragma unroll
  for (int dz = 0; dz < 2; ++dz) {
#pragma unroll
    for (int dy = 0; dy < 2; ++dy) {
      float wzy = wzs[dz] * wys[dy];
      int base = (zq[dz] * HH + yq[dy]) * WW;
#pragma unroll
      for (int dx = 0; dx < 2; ++dx) {
        float w = wzy * wxs[dx];
        int lin = base + xq[dx];
        s0 += w * ff[lin];
        s1 += w * ff[DHW + lin];
        s2 += w * ff[2 * DHW + lin];
      }
    }
  }
  float* cp = comp + (size_t)b * DHW * ST + (size_t)v * ST;
  if (ST == 4) {
    float4 o = make_float4(fz + s0, fy + s1, fx + s2, 0.f);
    *(float4*)cp = o;
  } else {
    cp[0] = fz + s0;
    cp[1] = fy + s1;
    cp[2] = fx + s2;
  }
}

// corner load: 3 channels at one voxel from interleaved field
template <int ST>
__device__ __forceinline__ void ldc(const float* __restrict__ p, float o[3]) {
  if (ST == 4) {
    float4 v = *(const float4*)p;
    o[0] = v.x; o[1] = v.y; o[2] = v.z;
  } else {
    o[0] = p[0]; o[1] = p[1]; o[2] = p[2];
  }
}

// ---------------------------------------------------------------------------
// Kernel 2: per-point penalty  sum_a |s(p+dx_a e_a) - s(p)|^2 / dx_a^2.
// Base 2x2x2 corner cube loaded once; shifted samples reuse it unless the
// shift crosses a voxel boundary (then load only the 4 new-plane corners).
// ---------------------------------------------------------------------------
template <int ST>
__global__ __launch_bounds__(256) void penalty_kernel(
    const float* __restrict__ comp,
    const int* __restrict__ idx,
    float* __restrict__ partial) {
  const float SX = (float)WW / (float)(WW - 1);
  const float SY = (float)HH / (float)(HH - 1);
  const float SZ = (float)DD / (float)(DD - 1);
  const float dxa = (float)(DD - 1) * 1e-3f;  // shift on x coordinate
  const float dyb = (float)(HH - 1) * 1e-3f;  // shift on y coordinate
  const float dzc = (float)(WW - 1) * 1e-3f;  // shift on z coordinate
  const float inv_dxa2 = 1.f / (dxa * dxa);
  const float inv_dyb2 = 1.f / (dyb * dyb);
  const float inv_dzc2 = 1.f / (dzc * dzc);

  int t = blockIdx.x * 256 + threadIdx.x;  // exact grid: NPBLK*256 == BB*NSUB_
  int b = t / NSUB_;
  int n = t - b * NSUB_;
  int id = idx[n];
  float px = (float)(id % WW);
  float py = (float)((id / WW) % HH);
  float pz = (float)(id / (WW * HH));
  const float* __restrict__ cp = comp + (size_t)b * DHW * ST;

  float ix = px * SX - 0.5f;
  float iy = py * SY - 0.5f;
  float iz = pz * SZ - 0.5f;
  float x0f = floorf(ix), y0f = floorf(iy), z0f = floorf(iz);
  float wx = ix - x0f, wy = iy - y0f, wz = iz - z0f;
  int x0 = (int)x0f, y0 = (int)y0f, z0 = (int)z0f;

  int xq[2], yq[2], zq[2];
  xq[0] = min(max(x0, 0), WW - 1);     xq[1] = min(max(x0 + 1, 0), WW - 1);
  yq[0] = min(max(y0, 0), HH - 1);     yq[1] = min(max(y0 + 1, 0), HH - 1);
  zq[0] = min(max(z0, 0), DD - 1);     zq[1] = min(max(z0 + 1, 0), DD - 1);
  float wxs[2] = {1.f - wx, wx};
  float wys[2] = {1.f - wy, wy};
  float wzs[2] = {1.f - wz, wz};

  // base corner cube C[dz][dy][dx][c]
  float C[2][2][2][3];
#pragma unroll
  for (int dz = 0; dz < 2; ++dz)
#pragma unroll
    for (int dy = 0; dy < 2; ++dy) {
      int base = (zq[dz] * HH + yq[dy]) * WW;
#pragma unroll
      for (int dx = 0; dx < 2; ++dx)
        ldc<ST>(cp + (size_t)(base + xq[dx]) * ST, C[dz][dy][dx]);
    }

  // base sample
  float s0[3] = {0.f, 0.f, 0.f};
#pragma unroll
  for (int dz = 0; dz < 2; ++dz)
#pragma unroll
    for (int dy = 0; dy < 2; ++dy) {
      float wzy = wzs[dz] * wys[dy];
#pragma unroll
      for (int dx = 0; dx < 2; ++dx) {
        float w = wzy * wxs[dx];
#pragma unroll
        for (int c = 0; c < 3; ++c) s0[c] += w * C[dz][dy][dx][c];
      }
    }

  float acc = 0.f;

  // ---- x shift ----
  {
    float ix2 = ix + dxa * SX;
    int x0b = (int)floorf(ix2);
    float w1 = ix2 - (float)x0b;  // weight on far corner
    float sa[3] = {0.f, 0.f, 0.f};
    if (x0b == x0) {
      float ws[2] = {1.f - w1, w1};
#pragma unroll
      for (int dz = 0; dz < 2; ++dz)
#pragma unroll
        for (int dy = 0; dy < 2; ++dy) {
          float wzy = wzs[dz] * wys[dy];
#pragma unroll
          for (int dx = 0; dx < 2; ++dx) {
            float w = wzy * ws[dx];
#pragma unroll
            for (int c = 0; c < 3; ++c) sa[c] += w * C[dz][dy][dx][c];
          }
        }
    } else {  // x0b == x0+1: corners x0+1 (have) and x0+2 (load)
      int xq2 = min(x0 + 2, WW - 1);
#pragma unroll
      for (int dz = 0; dz < 2; ++dz)
#pragma unroll
        for (int dy = 0; dy < 2; ++dy) {
          float wzy = wzs[dz] * wys[dy];
          float N[3];
          ldc<ST>(cp + (size_t)((zq[dz] * HH + yq[dy]) * WW + xq2) * ST, N);
#pragma unroll
          for (int c = 0; c < 3; ++c)
            sa[c] += wzy * ((1.f - w1) * C[dz][dy][1][c] + w1 * N[c]);
        }
    }
    float d0 = sa[0] - s0[0], d1 = sa[1] - s0[1], d2 = sa[2] - s0[2];
    acc += (d0 * d0 + d1 * d1 + d2 * d2) * inv_dxa2;
  }

  // ---- y shift ----
  {
    float iy2 = iy + dyb * SY;
    int y0b = (int)floorf(iy2);
    float w1 = iy2 - (float)y0b;
    float sa[3] = {0.f, 0.f, 0.f};
    if (y0b == y0) {
      float ws[2] = {1.f - w1, w1};
#pragma unroll
      for (int dz = 0; dz < 2; ++dz)
#pragma unroll
        for (int dy = 0; dy < 2; ++dy) {
          float wzy = wzs[dz] * ws[dy];
#pragma unroll
          for (int dx = 0; dx < 2; ++dx) {
            float w = wzy * wxs[dx];
#pragma unroll
            for (int c = 0; c < 3; ++c) sa[c] += w * C[dz][dy][dx][c];
          }
        }
    } else {
      int yq2 = min(y0 + 2, HH - 1);
#pragma unroll
      for (int dz = 0; dz < 2; ++dz) {
        int base = (zq[dz] * HH + yq2) * WW;
#pragma unroll
        for (int dx = 0; dx < 2; ++dx) {
          float N[3];
          ldc<ST>(cp + (size_t)(base + xq[dx]) * ST, N);
          float wzx = wzs[dz] * wxs[dx];
#pragma unroll
          for (int c = 0; c < 3; ++c)
            sa[c] += wzx * ((1.f - w1) * C[dz][1][dx][c] + w1 * N[c]);
        }
      }
    }
    float d0 = sa[0] - s0[0], d1 = sa[1] - s0[1], d2 = sa[2] - s0[2];
    acc += (d0 * d0 + d1 * d1 + d2 * d2) * inv_dyb2;
  }

  // ---- z shift ----
  {
    float iz2 = iz + dzc * SZ;
    int z0b = (int)floorf(iz2);
    float w1 = iz2 - (float)z0b;
    float sa[3] = {0.f, 0.f, 0.f};
    if (z0b == z0) {
      float ws[2] = {1.f - w1, w1};
#pragma unroll
      for (int dz = 0; dz < 2; ++dz)
#pragma unroll
        for (int dy = 0; dy < 2; ++dy) {
          float wzy = ws[dz] * wys[dy];
#pragma unroll
          for (int dx = 0; dx < 2; ++dx) {
            float w = wzy * wxs[dx];
#pragma unroll
            for (int c = 0; c < 3; ++c) sa[c] += w * C[dz][dy][dx][c];
          }
        }
    } else {
      int zq2 = min(z0 + 2, DD - 1);
#pragma unroll
      for (int dy = 0; dy < 2; ++dy) {
        int base = (zq2 * HH + yq[dy]) * WW;
#pragma unroll
        for (int dx = 0; dx < 2; ++dx) {
          float N[3];
          ldc<ST>(cp + (size_t)(base + xq[dx]) * ST, N);
          float wyx = wys[dy] * wxs[dx];
#pragma unroll
          for (int c = 0; c < 3; ++c)
            sa[c] += wyx * ((1.f - w1) * C[1][dy][dx][c] + w1 * N[c]);
        }
      }
    }
    float d0 = sa[0] - s0[0], d1 = sa[1] - s0[1], d2 = sa[2] - s0[2];
    acc += (d0 * d0 + d1 * d1 + d2 * d2) * inv_dzc2;
  }

  // block reduce (wave64 shuffle + LDS across 4 waves)
#pragma unroll
  for (int off = 32; off > 0; off >>= 1) acc += __shfl_down(acc, off);
  __shared__ float smem[4];
  int lane = threadIdx.x & 63, wid = threadIdx.x >> 6;
  if (lane == 0) smem[wid] = acc;
  __syncthreads();
  if (threadIdx.x == 0)
    partial[blockIdx.x] = smem[0] + smem[1] + smem[2] + smem[3];
}

__global__ __launch_bounds__(256) void finalize_kernel(
    const float* __restrict__ partial, float* __restrict__ out) {
  float v = 0.f;
  for (int i = threadIdx.x; i < NPBLK; i += 256) v += partial[i];
#pragma unroll
  for (int off = 32; off > 0; off >>= 1) v += __shfl_down(v, off);
  __shared__ float smem[4];
  int lane = threadIdx.x & 63, wid = threadIdx.x >> 6;
  if (lane == 0) smem[wid] = v;
  __syncthreads();
  if (threadIdx.x == 0) {
    float tot = smem[0] + smem[1] + smem[2] + smem[3];
    out[0] = tot / (float)(BB * NSUB_);
  }
}

// ---------------------------------------------------------------------------
extern "C" void kernel_launch(void* const* d_in, const int* in_sizes, int n_in,
                              void* d_out, int out_size, void* d_ws, size_t ws_size,
                              hipStream_t stream) {
  const float* flow_fwd = (const float*)d_in[0];
  const float* flow_inv = (const float*)d_in[1];
  const int*   idx      = (const int*)d_in[2];
  float* out = (float*)d_out;

  float* comp = (float*)d_ws;
  size_t need4 = (size_t)BB * DHW * 4 * 4 + (size_t)NPBLK * 4;
  bool use4 = ws_size >= need4;

  if (use4) {
    float* partial = comp + (size_t)BB * DHW * 4;
    compose_kernel<4><<<(BB * DHW + 255) / 256, 256, 0, stream>>>(flow_fwd, flow_inv, comp);
    penalty_kernel<4><<<NPBLK, 256, 0, stream>>>(comp, idx, partial);
    finalize_kernel<<<1, 256, 0, stream>>>(partial, out);
  } else {
    float* partial = comp + (size_t)BB * DHW * 3;
    compose_kernel<3><<<(BB * DHW + 255) / 256, 256, 0, stream>>>(flow_fwd, flow_inv, comp);
    penalty_kernel<3><<<NPBLK, 256, 0, stream>>>(comp, idx, partial);
    finalize_kernel<<<1, 256, 0, stream>>>(partial, out);
  }
}

// Round 3
// 452.815 us; speedup vs baseline: 3.6299x; 1.1192x over previous
//
#include <hip/hip_runtime.h>

// Problem geometry (fixed by the reference).
#define DD 160
#define HH 192
#define WW 160
constexpr int DHW   = DD * HH * WW;   // 4,915,200
constexpr int NSUB_ = DHW / 8;        // 614,400
constexpr int BB    = 2;
constexpr int NPBLK = 4800;           // penalty: 1 pt/thread, 4800*256 = 2*NSUB_

// ---------------------------------------------------------------------------
// Kernel 0: planar [3][DHW] -> interleaved float4 [DHW] (streaming, BW-bound)
// ---------------------------------------------------------------------------
__global__ __launch_bounds__(256) void interleave_kernel(
    const float* __restrict__ ff, float4* __restrict__ ffi) {
  int tid = blockIdx.x * 256 + threadIdx.x;
  if (tid >= BB * DHW) return;
  int b = tid / DHW;
  int v = tid - b * DHW;
  const float* f = ff + (size_t)b * 3 * DHW;
  ffi[(size_t)b * DHW + v] = make_float4(f[v], f[DHW + v], f[2 * DHW + v], 0.f);
}

// ---------------------------------------------------------------------------
// Kernel 1: comp = flow_inv + STN(flow_fwd, flow_inv), float4-interleaved out.
// align_corners=True => sample location is voxel+flow directly; zeros padding
// via clamped index + masked weight. Gathers from INTERLEAVED ffi (float4).
// ---------------------------------------------------------------------------
__global__ __launch_bounds__(256) void compose_kernel(
    const float4* __restrict__ ffi,
    const float* __restrict__ flow_inv,
    float4* __restrict__ comp) {
  int tid = blockIdx.x * 256 + threadIdx.x;
  if (tid >= BB * DHW) return;
  int b = tid / DHW;
  int v = tid - b * DHW;
  int x = v % WW;
  int y = (v / WW) % HH;
  int z = v / (WW * HH);

  const float* fi = flow_inv + (size_t)b * 3 * DHW;
  const float4* fv = ffi + (size_t)b * DHW;
  float fz = fi[v];
  float fy = fi[DHW + v];
  float fx = fi[2 * DHW + v];
  float lx = (float)x + fx, ly = (float)y + fy, lz = (float)z + fz;

  float x0f = floorf(lx), y0f = floorf(ly), z0f = floorf(lz);
  float wx = lx - x0f, wy = ly - y0f, wz = lz - z0f;
  int x0 = (int)x0f, y0 = (int)y0f, z0 = (int)z0f;

  int xq[2], yq[2], zq[2];
  float wxs[2], wys[2], wzs[2];
  xq[0] = min(max(x0, 0), WW - 1);     xq[1] = min(max(x0 + 1, 0), WW - 1);
  yq[0] = min(max(y0, 0), HH - 1);     yq[1] = min(max(y0 + 1, 0), HH - 1);
  zq[0] = min(max(z0, 0), DD - 1);     zq[1] = min(max(z0 + 1, 0), DD - 1);
  wxs[0] = (x0 >= 0) ? 1.f - wx : 0.f;          // x0 < WW always when x0>=0? no:
  wxs[0] = (x0 >= 0 && x0 < WW) ? 1.f - wx : 0.f;
  wxs[1] = (x0 + 1 >= 0 && x0 + 1 < WW) ? wx : 0.f;
  wys[0] = (y0 >= 0 && y0 < HH) ? 1.f - wy : 0.f;
  wys[1] = (y0 + 1 >= 0 && y0 + 1 < HH) ? wy : 0.f;
  wzs[0] = (z0 >= 0 && z0 < DD) ? 1.f - wz : 0.f;
  wzs[1] = (z0 + 1 >= 0 && z0 + 1 < DD) ? wz : 0.f;

  // 8 float4 gathers, fully unrolled so loads issue before the FMA chain
  float4 c000 = fv[(zq[0] * HH + yq[0]) * WW + xq[0]];
  float4 c001 = fv[(zq[0] * HH + yq[0]) * WW + xq[1]];
  float4 c010 = fv[(zq[0] * HH + yq[1]) * WW + xq[0]];
  float4 c011 = fv[(zq[0] * HH + yq[1]) * WW + xq[1]];
  float4 c100 = fv[(zq[1] * HH + yq[0]) * WW + xq[0]];
  float4 c101 = fv[(zq[1] * HH + yq[0]) * WW + xq[1]];
  float4 c110 = fv[(zq[1] * HH + yq[1]) * WW + xq[0]];
  float4 c111 = fv[(zq[1] * HH + yq[1]) * WW + xq[1]];

  float w000 = wzs[0] * wys[0] * wxs[0];
  float w001 = wzs[0] * wys[0] * wxs[1];
  float w010 = wzs[0] * wys[1] * wxs[0];
  float w011 = wzs[0] * wys[1] * wxs[1];
  float w100 = wzs[1] * wys[0] * wxs[0];
  float w101 = wzs[1] * wys[0] * wxs[1];
  float w110 = wzs[1] * wys[1] * wxs[0];
  float w111 = wzs[1] * wys[1] * wxs[1];

  float s0 = w000 * c000.x + w001 * c001.x + w010 * c010.x + w011 * c011.x +
             w100 * c100.x + w101 * c101.x + w110 * c110.x + w111 * c111.x;
  float s1 = w000 * c000.y + w001 * c001.y + w010 * c010.y + w011 * c011.y +
             w100 * c100.y + w101 * c101.y + w110 * c110.y + w111 * c111.y;
  float s2 = w000 * c000.z + w001 * c001.z + w010 * c010.z + w011 * c011.z +
             w100 * c100.z + w101 * c101.z + w110 * c110.z + w111 * c111.z;

  comp[(size_t)b * DHW + v] = make_float4(fz + s0, fy + s1, fx + s2, 0.f);
}

// corner load: 3 channels at one voxel from interleaved float4 field
__device__ __forceinline__ void ldc(const float4* __restrict__ p, float o[3]) {
  float4 v = *p;
  o[0] = v.x; o[1] = v.y; o[2] = v.z;
}

// ---------------------------------------------------------------------------
// Kernel 2: per-point penalty  sum_a |s(p+dx_a e_a) - s(p)|^2 / dx_a^2.
// Base 2x2x2 corner cube loaded once; shifted samples reuse it unless the
// shift crosses a voxel boundary (then load only the 4 new-plane corners).
// ---------------------------------------------------------------------------
__global__ __launch_bounds__(256) void penalty_kernel(
    const float4* __restrict__ comp,
    const int* __restrict__ idx,
    float* __restrict__ partial) {
  const float SX = (float)WW / (float)(WW - 1);
  const float SY = (float)HH / (float)(HH - 1);
  const float SZ = (float)DD / (float)(DD - 1);
  const float dxa = (float)(DD - 1) * 1e-3f;  // shift on x coordinate
  const float dyb = (float)(HH - 1) * 1e-3f;  // shift on y coordinate
  const float dzc = (float)(WW - 1) * 1e-3f;  // shift on z coordinate
  const float inv_dxa2 = 1.f / (dxa * dxa);
  const float inv_dyb2 = 1.f / (dyb * dyb);
  const float inv_dzc2 = 1.f / (dzc * dzc);

  int t = blockIdx.x * 256 + threadIdx.x;  // exact grid: NPBLK*256 == BB*NSUB_
  int b = t / NSUB_;
  int n = t - b * NSUB_;
  int id = idx[n];
  float px = (float)(id % WW);
  float py = (float)((id / WW) % HH);
  float pz = (float)(id / (WW * HH));
  const float4* __restrict__ cp = comp + (size_t)b * DHW;

  float ix = px * SX - 0.5f;
  float iy = py * SY - 0.5f;
  float iz = pz * SZ - 0.5f;
  float x0f = floorf(ix), y0f = floorf(iy), z0f = floorf(iz);
  float wx = ix - x0f, wy = iy - y0f, wz = iz - z0f;
  int x0 = (int)x0f, y0 = (int)y0f, z0 = (int)z0f;

  int xq[2], yq[2], zq[2];
  xq[0] = min(max(x0, 0), WW - 1);     xq[1] = min(max(x0 + 1, 0), WW - 1);
  yq[0] = min(max(y0, 0), HH - 1);     yq[1] = min(max(y0 + 1, 0), HH - 1);
  zq[0] = min(max(z0, 0), DD - 1);     zq[1] = min(max(z0 + 1, 0), DD - 1);
  float wxs[2] = {1.f - wx, wx};
  float wys[2] = {1.f - wy, wy};
  float wzs[2] = {1.f - wz, wz};

  // base corner cube C[dz][dy][dx][c]
  float C[2][2][2][3];
#pragma unroll
  for (int dz = 0; dz < 2; ++dz)
#pragma unroll
    for (int dy = 0; dy < 2; ++dy) {
      int base = (zq[dz] * HH + yq[dy]) * WW;
#pragma unroll
      for (int dx = 0; dx < 2; ++dx)
        ldc(cp + (size_t)(base + xq[dx]), C[dz][dy][dx]);
    }

  // base sample
  float s0[3] = {0.f, 0.f, 0.f};
#pragma unroll
  for (int dz = 0; dz < 2; ++dz)
#pragma unroll
    for (int dy = 0; dy < 2; ++dy) {
      float wzy = wzs[dz] * wys[dy];
#pragma unroll
      for (int dx = 0; dx < 2; ++dx) {
        float w = wzy * wxs[dx];
#pragma unroll
        for (int c = 0; c < 3; ++c) s0[c] += w * C[dz][dy][dx][c];
      }
    }

  float acc = 0.f;

  // ---- x shift ----
  {
    float ix2 = ix + dxa * SX;
    int x0b = (int)floorf(ix2);
    float w1 = ix2 - (float)x0b;  // weight on far corner
    float sa[3] = {0.f, 0.f, 0.f};
    if (x0b == x0) {
      float ws[2] = {1.f - w1, w1};
#pragma unroll
      for (int dz = 0; dz < 2; ++dz)
#pragma unroll
        for (int dy = 0; dy < 2; ++dy) {
          float wzy = wzs[dz] * wys[dy];
#pragma unroll
          for (int dx = 0; dx < 2; ++dx) {
            float w = wzy * ws[dx];
#pragma unroll
            for (int c = 0; c < 3; ++c) sa[c] += w * C[dz][dy][dx][c];
          }
        }
    } else {  // x0b == x0+1: corners x0+1 (have) and x0+2 (load)
      int xq2 = min(x0 + 2, WW - 1);
#pragma unroll
      for (int dz = 0; dz < 2; ++dz)
#pragma unroll
        for (int dy = 0; dy < 2; ++dy) {
          float wzy = wzs[dz] * wys[dy];
          float N[3];
          ldc(cp + (size_t)((zq[dz] * HH + yq[dy]) * WW + xq2), N);
#pragma unroll
          for (int c = 0; c < 3; ++c)
            sa[c] += wzy * ((1.f - w1) * C[dz][dy][1][c] + w1 * N[c]);
        }
    }
    float d0 = sa[0] - s0[0], d1 = sa[1] - s0[1], d2 = sa[2] - s0[2];
    acc += (d0 * d0 + d1 * d1 + d2 * d2) * inv_dxa2;
  }

  // ---- y shift ----
  {
    float iy2 = iy + dyb * SY;
    int y0b = (int)floorf(iy2);
    float w1 = iy2 - (float)y0b;
    float sa[3] = {0.f, 0.f, 0.f};
    if (y0b == y0) {
      float ws[2] = {1.f - w1, w1};
#pragma unroll
      for (int dz = 0; dz < 2; ++dz)
#pragma unroll
        for (int dy = 0; dy < 2; ++dy) {
          float wzy = wzs[dz] * ws[dy];
#pragma unroll
          for (int dx = 0; dx < 2; ++dx) {
            float w = wzy * wxs[dx];
#pragma unroll
            for (int c = 0; c < 3; ++c) sa[c] += w * C[dz][dy][dx][c];
          }
        }
    } else {
      int yq2 = min(y0 + 2, HH - 1);
#pragma unroll
      for (int dz = 0; dz < 2; ++dz) {
        int base = (zq[dz] * HH + yq2) * WW;
#pragma unroll
        for (int dx = 0; dx < 2; ++dx) {
          float N[3];
          ldc(cp + (size_t)(base + xq[dx]), N);
          float wzx = wzs[dz] * wxs[dx];
#pragma unroll
          for (int c = 0; c < 3; ++c)
            sa[c] += wzx * ((1.f - w1) * C[dz][1][dx][c] + w1 * N[c]);
        }
      }
    }
    float d0 = sa[0] - s0[0], d1 = sa[1] - s0[1], d2 = sa[2] - s0[2];
    acc += (d0 * d0 + d1 * d1 + d2 * d2) * inv_dyb2;
  }

  // ---- z shift ----
  {
    float iz2 = iz + dzc * SZ;
    int z0b = (int)floorf(iz2);
    float w1 = iz2 - (float)z0b;
    float sa[3] = {0.f, 0.f, 0.f};
    if (z0b == z0) {
      float ws[2] = {1.f - w1, w1};
#pragma unroll
      for (int dz = 0; dz < 2; ++dz)
#pragma unroll
        for (int dy = 0; dy < 2; ++dy) {
          float wzy = ws[dz] * wys[dy];
#pragma unroll
          for (int dx = 0; dx < 2; ++dx) {
            float w = wzy * wxs[dx];
#pragma unroll
            for (int c = 0; c < 3; ++c) sa[c] += w * C[dz][dy][dx][c];
          }
        }
    } else {
      int zq2 = min(z0 + 2, DD - 1);
#pragma unroll
      for (int dy = 0; dy < 2; ++dy) {
        int base = (zq2 * HH + yq[dy]) * WW;
#pragma unroll
        for (int dx = 0; dx < 2; ++dx) {
          float N[3];
          ldc(cp + (size_t)(base + xq[dx]), N);
          float wyx = wys[dy] * wxs[dx];
#pragma unroll
          for (int c = 0; c < 3; ++c)
            sa[c] += wyx * ((1.f - w1) * C[1][dy][dx][c] + w1 * N[c]);
        }
      }
    }
    float d0 = sa[0] - s0[0], d1 = sa[1] - s0[1], d2 = sa[2] - s0[2];
    acc += (d0 * d0 + d1 * d1 + d2 * d2) * inv_dzc2;
  }

  // block reduce (wave64 shuffle + LDS across 4 waves)
#pragma unroll
  for (int off = 32; off > 0; off >>= 1) acc += __shfl_down(acc, off);
  __shared__ float smem[4];
  int lane = threadIdx.x & 63, wid = threadIdx.x >> 6;
  if (lane == 0) smem[wid] = acc;
  __syncthreads();
  if (threadIdx.x == 0)
    partial[blockIdx.x] = smem[0] + smem[1] + smem[2] + smem[3];
}

__global__ __launch_bounds__(256) void finalize_kernel(
    const float* __restrict__ partial, float* __restrict__ out) {
  float v = 0.f;
  for (int i = threadIdx.x; i < NPBLK; i += 256) v += partial[i];
#pragma unroll
  for (int off = 32; off > 0; off >>= 1) v += __shfl_down(v, off);
  __shared__ float smem[4];
  int lane = threadIdx.x & 63, wid = threadIdx.x >> 6;
  if (lane == 0) smem[wid] = v;
  __syncthreads();
  if (threadIdx.x == 0) {
    float tot = smem[0] + smem[1] + smem[2] + smem[3];
    out[0] = tot / (float)(BB * NSUB_);
  }
}

// ---------------------------------------------------------------------------
extern "C" void kernel_launch(void* const* d_in, const int* in_sizes, int n_in,
                              void* d_out, int out_size, void* d_ws, size_t ws_size,
                              hipStream_t stream) {
  const float* flow_fwd = (const float*)d_in[0];
  const float* flow_inv = (const float*)d_in[1];
  const int*   idx      = (const int*)d_in[2];
  float* out = (float*)d_out;

  // ws layout: comp [BB*DHW float4] | ffi [BB*DHW float4] | partial [NPBLK f32]
  float4* comp = (float4*)d_ws;
  float4* ffi  = comp + (size_t)BB * DHW;
  float*  partial = (float*)(ffi + (size_t)BB * DHW);

  int nblk = (BB * DHW + 255) / 256;
  interleave_kernel<<<nblk, 256, 0, stream>>>(flow_fwd, ffi);
  compose_kernel<<<nblk, 256, 0, stream>>>(ffi, flow_inv, comp);
  penalty_kernel<<<NPBLK, 256, 0, stream>>>(comp, idx, partial);
  finalize_kernel<<<1, 256, 0, stream>>>(partial, out);
}